// Round 7
// baseline (193.146 us; speedup 1.0000x reference)
//
#include <hip/hip_runtime.h>
#include <hip/hip_bf16.h>
#include <math.h>

#define D      256
#define N2     8192
#define NHALF  4096
#define NBLK   1024
#define TILE   128
#define BK     32
#define NCH    8       // 256 / BK
#define LDW    32      // packed rows (64 B); XOR-swizzled 16B units -> 2-way banks (free)

typedef __bf16 bf16x8_t __attribute__((ext_vector_type(8)));
typedef __bf16 bf16x4_t __attribute__((ext_vector_type(4)));
typedef float  f32x4_t  __attribute__((ext_vector_type(4)));

// ---------------- kernel 1: fused normalize + positives + denom/ticket zero --------
__global__ __launch_bounds__(256) void prep_kernel(const float* __restrict__ a,
                                                   const float* __restrict__ b,
                                                   __bf16* __restrict__ zb,
                                                   float* __restrict__ g_pos,
                                                   float* __restrict__ g_denom,
                                                   unsigned* __restrict__ g_ticket) {
    const int tid = threadIdx.x;
    const int gt  = blockIdx.x * 256 + tid;
    if (gt < N2) g_denom[gt] = 0.0f;
    if (gt == 0) *g_ticket = 0u;

    const int w = blockIdx.x * 4 + (tid >> 6);  // pair row in [0, NHALF)
    const int l = tid & 63;
    float4 x = ((const float4*)(a + (size_t)w * D))[l];
    float4 y = ((const float4*)(b + (size_t)w * D))[l];
    float sxx = x.x * x.x + x.y * x.y + x.z * x.z + x.w * x.w;
    float syy = y.x * y.x + y.y * y.y + y.z * y.z + y.w * y.w;
    float sxy = x.x * y.x + x.y * y.y + x.z * y.z + x.w * y.w;
    #pragma unroll
    for (int off = 32; off; off >>= 1) {
        sxx += __shfl_xor(sxx, off, 64);
        syy += __shfl_xor(syy, off, 64);
        sxy += __shfl_xor(sxy, off, 64);
    }
    const float rx = 1.0f / fmaxf(sqrtf(sxx), 1e-8f);
    const float ry = 1.0f / fmaxf(sqrtf(syy), 1e-8f);

    bf16x4_t ox, oy;
    ox[0] = (__bf16)(x.x * rx); ox[1] = (__bf16)(x.y * rx);
    ox[2] = (__bf16)(x.z * rx); ox[3] = (__bf16)(x.w * rx);
    oy[0] = (__bf16)(y.x * ry); oy[1] = (__bf16)(y.y * ry);
    oy[2] = (__bf16)(y.z * ry); oy[3] = (__bf16)(y.w * ry);
    *(bf16x4_t*)(zb + (size_t)w * D + l * 4)           = ox;
    *(bf16x4_t*)(zb + (size_t)(w + NHALF) * D + l * 4) = oy;

    if (l == 0) {
        const float p = sxy * rx * ry;
        g_pos[w]         = p;
        g_pos[w + NHALF] = p;
    }
}

// ---------------- kernel 2: sim (4 tiles/block, 4 blocks/CU) + last-block fin ------
// Round-5 post-mortem: 2 blocks/CU barrier-locks all 8 waves into the same phase, so
// LDS-read (~20us), MFMA (~16.5us) and VALU/exp serialize -> the m93 rung (66us).
// This round: BK=32, packed 64B LDS rows with XOR-swizzled 16B units (2-way banks =
// free) -> 32KB dbuf -> 4 desynced blocks/CU so the pipes overlap across blocks.
// fin is fused via a device-scope ticket: the last block to finish reduces the loss
// (order-independent; no cooperative launch -- round 6's coop launch silently failed
// under graph capture, absmax 9.0 == "kernel never ran").
__global__ __launch_bounds__(256, 4) void sim_kernel(const __bf16* __restrict__ zb,
                                                     float* __restrict__ g_denom,
                                                     const float* __restrict__ g_pos,
                                                     unsigned* __restrict__ g_ticket,
                                                     float* __restrict__ out) {
    __shared__ __bf16 ldsA[2][TILE * LDW];
    __shared__ __bf16 ldsB[2][TILE * LDW];
    __shared__ float  sw[4];
    __shared__ bool   amLast;

    const int tid    = threadIdx.x;
    const int bx     = blockIdx.x;
    const int l      = tid & 63;
    const int lane15 = l & 15;
    const int quad   = l >> 4;
    const int w      = tid >> 6;
    const int wr     = (w >> 1) * 64;          // wave row offset in tile
    const int wc     = (w & 1) * 64;           // wave col offset in tile

    // staging map: thread -> rows (sr, sr+64), 16B unit sln; physical unit sln^swz(row)
    const int sr   = tid >> 2;                 // 0..63
    const int sln  = tid & 3;
    const int swzs = (sr ^ (sr >> 2)) & 3;     // identical for sr and sr+64
    const int wof0 = sr * LDW + ((sln ^ swzs) * 8);
    const int wof1 = (sr + 64) * LDW + ((sln ^ swzs) * 8);

    for (int tl = bx; tl < 64 * 64; tl += NBLK) {
        const int bi = tl >> 6;
        const int bj = tl & 63;
        const __bf16* zbA = zb + (size_t)(bi * TILE) * D;
        const __bf16* zbB = zb + (size_t)(bj * TILE) * D;

        bf16x8_t sa0, sa1, sb0, sb1;
        auto load_regs = [&](int c) {
            const int k0 = c * BK;
            const __bf16* A0 = zbA + (size_t)sr * D + k0 + sln * 8;
            const __bf16* B0 = zbB + (size_t)sr * D + k0 + sln * 8;
            sa0 = *(const bf16x8_t*)A0;
            sa1 = *(const bf16x8_t*)(A0 + (size_t)64 * D);
            sb0 = *(const bf16x8_t*)B0;
            sb1 = *(const bf16x8_t*)(B0 + (size_t)64 * D);
        };
        auto write_lds = [&](int buf) {
            *(bf16x8_t*)&ldsA[buf][wof0] = sa0;
            *(bf16x8_t*)&ldsA[buf][wof1] = sa1;
            *(bf16x8_t*)&ldsB[buf][wof0] = sb0;
            *(bf16x8_t*)&ldsB[buf][wof1] = sb1;
        };

        f32x4_t acc[4][4];
        #pragma unroll
        for (int mi = 0; mi < 4; ++mi)
            #pragma unroll
            for (int nj = 0; nj < 4; ++nj)
                acc[mi][nj] = (f32x4_t){0.f, 0.f, 0.f, 0.f};

        auto compute = [&](int buf) {
            bf16x8_t af[4], bff[4];
            #pragma unroll
            for (int mi = 0; mi < 4; ++mi) {
                const int row = wr + mi * 16 + lane15;
                af[mi] = *(const bf16x8_t*)&ldsA[buf][row * LDW + ((quad ^ ((row ^ (row >> 2)) & 3)) * 8)];
            }
            #pragma unroll
            for (int nj = 0; nj < 4; ++nj) {
                const int row = wc + nj * 16 + lane15;
                bff[nj] = *(const bf16x8_t*)&ldsB[buf][row * LDW + ((quad ^ ((row ^ (row >> 2)) & 3)) * 8)];
            }
            #pragma unroll
            for (int mi = 0; mi < 4; ++mi)
                #pragma unroll
                for (int nj = 0; nj < 4; ++nj)
                    acc[mi][nj] = __builtin_amdgcn_mfma_f32_16x16x32_bf16(bff[nj], af[mi], acc[mi][nj], 0, 0, 0);
        };

        // prologue (safe: previous tile's last compute used buf 1, then barrier)
        load_regs(0);
        write_lds(0);
        __syncthreads();

        int cur = 0;
        #pragma unroll
        for (int c = 0; c < NCH; ++c) {
            if (c + 1 < NCH) load_regs(c + 1);
            compute(cur);
            if (c + 1 < NCH) {
                write_lds(cur ^ 1);
                __syncthreads();
                cur ^= 1;
            }
        }

        // epilogue: e = exp(sim/T) = exp2(acc * 2/ln2); zero self-diag; row sums
        // acc[mi][nj]: row = bi*128+wr+mi*16+lane15, col = bj*128+wc+nj*16+quad*4+t
        const bool dw = (bi == bj) && (wr == wc);
        float rs[4] = {0.f, 0.f, 0.f, 0.f};
        #pragma unroll
        for (int mi = 0; mi < 4; ++mi) {
            #pragma unroll
            for (int nj = 0; nj < 4; ++nj) {
                #pragma unroll
                for (int t = 0; t < 4; ++t) {
                    float e = exp2f(acc[mi][nj][t] * 2.8853900817779268f);
                    if (dw && mi == nj && (quad * 4 + t) == lane15) e = 0.0f;
                    rs[mi] += e;
                }
            }
        }
        #pragma unroll
        for (int mi = 0; mi < 4; ++mi) {
            rs[mi] += __shfl_xor(rs[mi], 16, 64);
            rs[mi] += __shfl_xor(rs[mi], 32, 64);
        }
        if (l < 16) {
            #pragma unroll
            for (int mi = 0; mi < 4; ++mi)
                atomicAdd(&g_denom[bi * TILE + wr + mi * 16 + l], rs[mi]);
        }
        __syncthreads();   // all waves done before next tile's prologue overwrite
    }

    // ---------------- last-block fin ----------------
    // __syncthreads above drained vmcnt for every wave -> this block's atomics are
    // complete at L2. Device-scope ACQ_REL ticket: the block observing NBLK-1 knows
    // all other blocks' atomics are complete too.
    if (tid == 0) {
        __threadfence();
        unsigned t = __hip_atomic_fetch_add(g_ticket, 1u, __ATOMIC_ACQ_REL,
                                            __HIP_MEMORY_SCOPE_AGENT);
        amLast = (t == NBLK - 1);
    }
    __syncthreads();
    if (!amLast) return;

    float local = 0.0f;
    for (int k = tid; k < N2; k += 256) {
        float dn = __hip_atomic_load(&g_denom[k], __ATOMIC_RELAXED,
                                     __HIP_MEMORY_SCOPE_AGENT);
        local += logf(dn) - 2.0f * g_pos[k];
    }
    #pragma unroll
    for (int off = 32; off; off >>= 1) local += __shfl_xor(local, off, 64);
    if (l == 0) sw[tid >> 6] = local;
    __syncthreads();
    if (tid == 0) out[0] = (sw[0] + sw[1] + sw[2] + sw[3]) / (float)N2;
}

extern "C" void kernel_launch(void* const* d_in, const int* in_sizes, int n_in,
                              void* d_out, int out_size, void* d_ws, size_t ws_size,
                              hipStream_t stream) {
    const float* emb_i = (const float*)d_in[0];
    const float* emb_j = (const float*)d_in[1];

    __bf16*   zb       = (__bf16*)d_ws;                                 // 4 MB
    float*    g_denom  = (float*)((char*)d_ws + (size_t)N2 * D * 2);    // 8192 fp32
    float*    g_pos    = g_denom + N2;                                  // 8192 fp32
    unsigned* g_ticket = (unsigned*)(g_pos + N2);                       // 1 u32
    float*    out      = (float*)d_out;

    prep_kernel<<<NHALF / 4, 256, 0, stream>>>(emb_i, emb_j, zb, g_pos, g_denom, g_ticket);
    sim_kernel<<<NBLK, 256, 0, stream>>>(zb, g_denom, g_pos, g_ticket, out);
}

// Round 8
// 147.767 us; speedup vs baseline: 1.3071x; 1.3071x over previous
//
#include <hip/hip_runtime.h>
#include <hip/hip_bf16.h>
#include <math.h>

#define D      256
#define N2     8192
#define NHALF  4096
#define NBLK   1024
#define TILE   128
#define BK     64
#define NCH    4       // 256 / BK
#define LROW   64      // LDS row length in bf16 (128 B) -- linear, global_load_lds dest

typedef __bf16 bf16x8_t __attribute__((ext_vector_type(8)));
typedef __bf16 bf16x4_t __attribute__((ext_vector_type(4)));
typedef float  f32x4_t  __attribute__((ext_vector_type(4)));

// global -> LDS direct, 16 B/lane (m97 rung). LDS dest is wave-uniform base + lane*16.
#define GL2LDS(g, l) __builtin_amdgcn_global_load_lds(                        \
        (const __attribute__((address_space(1))) void*)(g),                   \
        (__attribute__((address_space(3))) void*)(l), 16, 0, 0)

// ---------------- kernel 1: fused normalize + positives + denom/ticket zero --------
__global__ __launch_bounds__(256) void prep_kernel(const float* __restrict__ a,
                                                   const float* __restrict__ b,
                                                   __bf16* __restrict__ zb,
                                                   float* __restrict__ g_pos,
                                                   float* __restrict__ g_denom,
                                                   unsigned* __restrict__ g_ticket) {
    const int tid = threadIdx.x;
    const int gt  = blockIdx.x * 256 + tid;
    if (gt < N2) g_denom[gt] = 0.0f;
    if (gt == 0) *g_ticket = 0u;

    const int w = blockIdx.x * 4 + (tid >> 6);  // pair row in [0, NHALF)
    const int l = tid & 63;
    float4 x = ((const float4*)(a + (size_t)w * D))[l];
    float4 y = ((const float4*)(b + (size_t)w * D))[l];
    float sxx = x.x * x.x + x.y * x.y + x.z * x.z + x.w * x.w;
    float syy = y.x * y.x + y.y * y.y + y.z * y.z + y.w * y.w;
    float sxy = x.x * y.x + x.y * y.y + x.z * y.z + x.w * y.w;
    #pragma unroll
    for (int off = 32; off; off >>= 1) {
        sxx += __shfl_xor(sxx, off, 64);
        syy += __shfl_xor(syy, off, 64);
        sxy += __shfl_xor(sxy, off, 64);
    }
    const float rx = 1.0f / fmaxf(sqrtf(sxx), 1e-8f);
    const float ry = 1.0f / fmaxf(sqrtf(syy), 1e-8f);

    bf16x4_t ox, oy;
    ox[0] = (__bf16)(x.x * rx); ox[1] = (__bf16)(x.y * rx);
    ox[2] = (__bf16)(x.z * rx); ox[3] = (__bf16)(x.w * rx);
    oy[0] = (__bf16)(y.x * ry); oy[1] = (__bf16)(y.y * ry);
    oy[2] = (__bf16)(y.z * ry); oy[3] = (__bf16)(y.w * ry);
    *(bf16x4_t*)(zb + (size_t)w * D + l * 4)           = ox;
    *(bf16x4_t*)(zb + (size_t)(w + NHALF) * D + l * 4) = oy;

    if (l == 0) {
        const float p = sxy * rx * ry;
        g_pos[w]         = p;
        g_pos[w + NHALF] = p;
    }
}

// ---------------- kernel 2: sim, m97-style global_load_lds staging + ticket fin ----
// Round-7 post-mortem: __launch_bounds__(256,4) capped VGPR at 128 -> the 64-reg acc
// spilled to scratch (VGPR_Count=64, 230 MB HBM spill traffic, 137us HBM-bound).
// Reverted to (256,2) (round-5 proved 88 VGPR, no spill). This round climbs m93->m97:
// staging via global_load_lds width-16 (no ds_write, no reg round-trip, loads fly
// under MFMA until the barrier drain; guide-measured +69% on this exact structure).
// LDS is LINEAR [128][64] (global_load_lds writes base+lane*16); bank conflicts on
// ds_read_b128 (16 lanes same 128B-stride column = 16-way) are fixed by the m173/m201
// pattern: XOR-pre-swizzle the GLOBAL source unit (u ^= row&7) and read with the same
// XOR -> 2-way banks (free). fin fused via device-scope ticket (round-7-verified).
__global__ __launch_bounds__(256, 2) void sim_kernel(const __bf16* __restrict__ zb,
                                                     float* __restrict__ g_denom,
                                                     const float* __restrict__ g_pos,
                                                     unsigned* __restrict__ g_ticket,
                                                     float* __restrict__ out) {
    __shared__ __bf16 ldsA[2][TILE * LROW];
    __shared__ __bf16 ldsB[2][TILE * LROW];
    __shared__ float  sw[4];
    __shared__ bool   amLast;

    const int tid    = threadIdx.x;
    const int bx     = blockIdx.x;
    const int l      = tid & 63;
    const int lane15 = l & 15;
    const int quad   = l >> 4;
    const int w      = tid >> 6;
    const int wr     = (w >> 1) * 64;          // wave row offset in tile
    const int wc     = (w & 1) * 64;           // wave col offset in tile
    const int rx7    = lane15 & 7;             // read-side swizzle term (row & 7)

    // staging map: instruction i covers 8 rows; lane l -> row +(l>>3), src unit (l&7)^(l>>3)
    const int srow  = l >> 3;                  // 0..7, == row&7 (rows 8-aligned)
    const int sunit = (l & 7) ^ srow;          // XOR-pre-swizzled global 16B unit

    for (int tl = bx; tl < 64 * 64; tl += NBLK) {
        const int bi = tl >> 6;
        const int bj = tl & 63;
        const __bf16* zbA = zb + (size_t)(bi * TILE) * D;
        const __bf16* zbB = zb + (size_t)(bj * TILE) * D;

        auto stage = [&](int c, int buf) {
            const int k0 = c * BK;
            #pragma unroll
            for (int i = 0; i < 4; ++i) {
                const int rb = w * 32 + i * 8;                    // wave-uniform row base
                const __bf16* ga = zbA + (size_t)(rb + srow) * D + k0 + sunit * 8;
                const __bf16* gb = zbB + (size_t)(rb + srow) * D + k0 + sunit * 8;
                GL2LDS(ga, &ldsA[buf][rb * LROW]);
                GL2LDS(gb, &ldsB[buf][rb * LROW]);
            }
        };

        f32x4_t acc[4][4];
        #pragma unroll
        for (int mi = 0; mi < 4; ++mi)
            #pragma unroll
            for (int nj = 0; nj < 4; ++nj)
                acc[mi][nj] = (f32x4_t){0.f, 0.f, 0.f, 0.f};

        auto compute = [&](int buf) {
            #pragma unroll
            for (int ks = 0; ks < 2; ++ks) {
                bf16x8_t af[4], bff[4];
                #pragma unroll
                for (int mi = 0; mi < 4; ++mi) {
                    const int row = wr + mi * 16 + lane15;
                    const int u   = (ks * 4 + quad) ^ rx7;
                    af[mi] = *(const bf16x8_t*)&ldsA[buf][row * LROW + u * 8];
                }
                #pragma unroll
                for (int nj = 0; nj < 4; ++nj) {
                    const int row = wc + nj * 16 + lane15;
                    const int u   = (ks * 4 + quad) ^ rx7;
                    bff[nj] = *(const bf16x8_t*)&ldsB[buf][row * LROW + u * 8];
                }
                #pragma unroll
                for (int mi = 0; mi < 4; ++mi)
                    #pragma unroll
                    for (int nj = 0; nj < 4; ++nj)
                        acc[mi][nj] = __builtin_amdgcn_mfma_f32_16x16x32_bf16(bff[nj], af[mi], acc[mi][nj], 0, 0, 0);
            }
        };

        // prologue: stage chunk 0 (safe: prev tile's LDS reads drained by its last barrier)
        stage(0, 0);
        __syncthreads();

        int cur = 0;
        #pragma unroll
        for (int c = 0; c < NCH; ++c) {
            if (c + 1 < NCH) stage(c + 1, cur ^ 1);   // async under this chunk's MFMAs
            compute(cur);
            __syncthreads();                          // drains vmcnt -> next buf ready
            cur ^= 1;
        }

        // epilogue: e = exp(sim/T) = exp2(acc * 2/ln2); zero self-diag; row sums
        // acc[mi][nj]: row = bi*128+wr+mi*16+lane15, col = bj*128+wc+nj*16+quad*4+t
        const bool dw = (bi == bj) && (wr == wc);
        float rs[4] = {0.f, 0.f, 0.f, 0.f};
        #pragma unroll
        for (int mi = 0; mi < 4; ++mi) {
            #pragma unroll
            for (int nj = 0; nj < 4; ++nj) {
                #pragma unroll
                for (int t = 0; t < 4; ++t) {
                    float e = exp2f(acc[mi][nj][t] * 2.8853900817779268f);
                    if (dw && mi == nj && (quad * 4 + t) == lane15) e = 0.0f;
                    rs[mi] += e;
                }
            }
        }
        #pragma unroll
        for (int mi = 0; mi < 4; ++mi) {
            rs[mi] += __shfl_xor(rs[mi], 16, 64);
            rs[mi] += __shfl_xor(rs[mi], 32, 64);
        }
        if (l < 16) {
            #pragma unroll
            for (int mi = 0; mi < 4; ++mi)
                atomicAdd(&g_denom[bi * TILE + wr + mi * 16 + l], rs[mi]);
        }
    }

    // ---------------- last-block fin (round-7-verified) ----------------
    if (tid == 0) {
        __threadfence();
        unsigned t = __hip_atomic_fetch_add(g_ticket, 1u, __ATOMIC_ACQ_REL,
                                            __HIP_MEMORY_SCOPE_AGENT);
        amLast = (t == NBLK - 1);
    }
    __syncthreads();
    if (!amLast) return;

    float local = 0.0f;
    for (int k = tid; k < N2; k += 256) {
        float dn = __hip_atomic_load(&g_denom[k], __ATOMIC_RELAXED,
                                     __HIP_MEMORY_SCOPE_AGENT);
        local += logf(dn) - 2.0f * g_pos[k];
    }
    #pragma unroll
    for (int off = 32; off; off >>= 1) local += __shfl_xor(local, off, 64);
    if (l == 0) sw[tid >> 6] = local;
    __syncthreads();
    if (tid == 0) out[0] = (sw[0] + sw[1] + sw[2] + sw[3]) / (float)N2;
}

extern "C" void kernel_launch(void* const* d_in, const int* in_sizes, int n_in,
                              void* d_out, int out_size, void* d_ws, size_t ws_size,
                              hipStream_t stream) {
    const float* emb_i = (const float*)d_in[0];
    const float* emb_j = (const float*)d_in[1];

    __bf16*   zb       = (__bf16*)d_ws;                                 // 4 MB
    float*    g_denom  = (float*)((char*)d_ws + (size_t)N2 * D * 2);    // 8192 fp32
    float*    g_pos    = g_denom + N2;                                  // 8192 fp32
    unsigned* g_ticket = (unsigned*)(g_pos + N2);                       // 1 u32
    float*    out      = (float*)d_out;

    prep_kernel<<<NHALF / 4, 256, 0, stream>>>(emb_i, emb_j, zb, g_pos, g_denom, g_ticket);
    sim_kernel<<<NBLK, 256, 0, stream>>>(zb, g_denom, g_pos, g_ticket, out);
}